// Round 19
// baseline (302.173 us; speedup 1.0000x reference)
//
#include <hip/hip_runtime.h>
#include <hip/hip_bf16.h>
#include <math.h>

constexpr int B = 64, S = 1024, H = 1024;

typedef __attribute__((ext_vector_type(8))) short bf16x8;
typedef __attribute__((ext_vector_type(4))) float f32x4;

__device__ __forceinline__ unsigned pkbf2(float x, float y) {
    union { __hip_bfloat162 h; unsigned u; } r;
    r.h = __float22bfloat162_rn(float2{x, y});   // v_cvt_pk_bf16_f32 (RNE)
    return r.u;
}
__device__ __forceinline__ bf16x8 pack8(float4 a, float4 b) {
    union { unsigned u[4]; bf16x8 v; } r;
    r.u[0] = pkbf2(a.x, a.y);
    r.u[1] = pkbf2(a.z, a.w);
    r.u[2] = pkbf2(b.x, b.y);
    r.u[3] = pkbf2(b.z, b.w);
    return r.v;
}

__device__ __forceinline__ float tanh_fast(float x) {
    return 1.0f - 2.0f / (__expf(2.0f * x) + 1.0f);
}

__device__ __forceinline__ void gload_lds16(const void* g, void* l) {
    __builtin_amdgcn_global_load_lds(
        (const __attribute__((address_space(1))) unsigned int*)g,
        (__attribute__((address_space(3))) unsigned int*)(uintptr_t)l,
        16, 0, 0);
}

// ---------------------------------------------------------------------------
// Kernel 1: hb[b][o] = attn_b[o] + sum_h hidden[b,h] * attn_W[o,h]   (f32)
// ---------------------------------------------------------------------------
__global__ __launch_bounds__(256) void k_hproj(const float* __restrict__ hidden,
                                               const float* __restrict__ attn_W,
                                               const float* __restrict__ attn_b,
                                               float* __restrict__ hb) {
    int wid  = blockIdx.x * 4 + (threadIdx.x >> 6);
    int lane = threadIdx.x & 63;
    int b = wid >> 10;
    int o = wid & 1023;
    const float* hrow = hidden + (size_t)b * H;
    const float* wrow = attn_W + (size_t)o * (2 * H);
    float acc = 0.f;
#pragma unroll
    for (int k = 0; k < 4; ++k) {
        int idx = lane * 4 + k * 256;
        float4 hv = *(const float4*)(hrow + idx);
        float4 wv = *(const float4*)(wrow + idx);
        acc += hv.x * wv.x + hv.y * wv.y + hv.z * wv.z + hv.w * wv.w;
    }
#pragma unroll
    for (int off = 32; off > 0; off >>= 1) acc += __shfl_down(acc, off, 64);
    if (lane == 0) hb[(size_t)b * H + o] = acc + attn_b[o];
}

// ---------------------------------------------------------------------------
// Kernel 2 (LDS-image order): We -> bf16 spans. Span (Nblk, kt) = 32 KB,
// granule G = r*8 + gphys (r = o within 256), gphys = glog ^ (r&7),
// content = We[Nblk*256+r][kt*64 + glog*8 .. +7].  Staging to LDS is then a
// LINEAR copy and ds_read applies the XOR (rule #21-clean).
// ---------------------------------------------------------------------------
__global__ __launch_bounds__(256) void k_convW(const float* __restrict__ attn_W,
                                               short* __restrict__ WeB) {
    int blk = blockIdx.x;                 // 0..63 = Nblk*16 + kt
    int kt  = blk & 15;
    int Nblk = blk >> 4;
    int t = threadIdx.x;                  // r = t, 0..255
    int o = Nblk * 256 + t;
    const float* src = attn_W + (size_t)o * (2 * H) + H + kt * 64;
    short* dst = WeB + (size_t)blk * 16384;
#pragma unroll
    for (int j = 0; j < 8; ++j) {
        float4 a = *(const float4*)(src + j * 8);
        float4 c = *(const float4*)(src + j * 8 + 4);
        int gphys = j ^ (t & 7);
        *(bf16x8*)(dst + ((size_t)t * 8 + gphys) * 8) = pack8(a, c);
    }
}

// ---------------------------------------------------------------------------
// Kernel 2b (LDS-image order): enc -> bf16 spans. Span (Mblk, kt) = 16 KB,
// granule G = r*8 + gphys (r = row within 128), content = enc row
// (m = Mblk*128+r -> s,b), k = kt*64 + (gphys^(r&7))*8 .. +7.
// ---------------------------------------------------------------------------
__global__ __launch_bounds__(256) void k_convA(const float* __restrict__ enc,
                                               short* __restrict__ encA) {
    int blk = blockIdx.x;                 // 0..8191 = Mblk*16 + kt
    int kt   = blk & 15;
    int Mblk = blk >> 4;
    int t = threadIdx.x;
    int r   = t >> 1;                     // 0..127
    int kh2 = t & 1;                      // 32-k half
    int m = Mblk * 128 + r;
    int b = m >> 10, s = m & 1023;
    const float* src = enc + ((size_t)s * 64 + b) * 1024 + kt * 64 + kh2 * 32;
    short* dst = encA + (size_t)blk * 8192;
#pragma unroll
    for (int j = 0; j < 4; ++j) {
        float4 a = *(const float4*)(src + j * 8);
        float4 c = *(const float4*)(src + j * 8 + 4);
        int glog  = kh2 * 4 + j;
        int gphys = glog ^ (r & 7);
        *(bf16x8*)(dst + ((size_t)r * 8 + gphys) * 8) = pack8(a, c);
    }
}

// ---------------------------------------------------------------------------
// Kernel 3: LDS-staged MFMA GEMM, 3-slot ring, counted vmcnt (T3+T4).
// BM=128 x BN=256, 8 waves (2M x 4N), wave tile 64x64, BK=64.
// LDS = 3 x (A 16KB + B 32KB) = 144 KB -> 1 block/CU, 8 waves.
// Per K-tile: issue STAGE(kt+2) -> ds_read+MFMA(kt) -> vmcnt(6) -> s_barrier.
// Slot (kt+2)%3 == (kt-1)%3: its readers passed the kt-1 barrier (safe).
// Raw s_barrier (NOT __syncthreads) keeps the 6 staged loads in flight.
// Per-CU global traffic per K-tile: 48KB staged vs 128KB per-wave (r15) —
// the 2.7x L1/TA-port reduction that the 165us/37% plateau was pinned on.
// ---------------------------------------------------------------------------
__global__ __launch_bounds__(512, 1) void k_mfma_s(const short* __restrict__ encA,
                                                   const short* __restrict__ WeB,
                                                   const float* __restrict__ v_W,
                                                   const float* __restrict__ hb,
                                                   float* __restrict__ pscore) {
    __shared__ short AS[3 * 8192];    // 48 KB
    __shared__ short BS[3 * 16384];   // 96 KB
    __shared__ float red[128 * 4];    // 2 KB

    const int tid  = threadIdx.x;
    const int lane = tid & 63;
    const int wv   = tid >> 6;        // 0..7
    const int wr   = wv >> 2;         // 0..1  (M half)
    const int wc   = wv & 3;          // 0..3  (N quarter)
    const int t16  = lane & 15;
    const int q    = lane >> 4;

    const int L    = blockIdx.x;                  // 0..2047
    const int nbq  = (L >> 3) & 3;
    const int Mblk = (L & 7) | ((L >> 5) << 3);   // 0..511 (128 rows each)
    const int b    = Mblk >> 3;

    const short* aSrc0 = encA + (size_t)(Mblk * 16) * 8192;
    const short* bSrc0 = WeB  + (size_t)(nbq * 16) * 16384;

    // frag read offsets (shorts), within a slot
    const int swz = t16 & 7;
    int aoff[2][4], boff[2][4];
#pragma unroll
    for (int kh = 0; kh < 2; ++kh)
#pragma unroll
        for (int f = 0; f < 4; ++f) {
            int ra = wr * 64 + f * 16 + t16;
            aoff[kh][f] = (ra * 8 + ((kh * 4 + q) ^ swz)) * 8;
            int rb = wc * 64 + f * 16 + t16;
            boff[kh][f] = (rb * 8 + ((kh * 4 + q) ^ swz)) * 8;
        }

    f32x4 acc[4][4];
#pragma unroll
    for (int mf = 0; mf < 4; ++mf)
#pragma unroll
        for (int nf = 0; nf < 4; ++nf) acc[mf][nf] = (f32x4){0.f, 0.f, 0.f, 0.f};

    auto STAGE = [&](int kt) {
        const int slot = kt % 3;
        const short* as = aSrc0 + (size_t)kt * 8192;
        const short* bs = bSrc0 + (size_t)kt * 16384;
#pragma unroll
        for (int p = 0; p < 2; ++p)
            gload_lds16(as + ((size_t)p * 512 + tid) * 8,
                        &AS[slot * 8192 + (p * 512 + tid) * 8]);
#pragma unroll
        for (int p = 0; p < 4; ++p)
            gload_lds16(bs + ((size_t)p * 512 + tid) * 8,
                        &BS[slot * 16384 + (p * 512 + tid) * 8]);
    };

    // prologue: stage kt0, kt1; ensure kt0 landed (6 of 12 may remain)
    STAGE(0);
    STAGE(1);
    asm volatile("s_waitcnt vmcnt(6)" ::: "memory");
    __builtin_amdgcn_s_barrier();
    asm volatile("" ::: "memory");

    for (int kt = 0; kt < 16; ++kt) {
        if (kt + 2 < 16) STAGE(kt + 2);

        const int slot = kt % 3;
        const short* Ab = &AS[slot * 8192];
        const short* Bb = &BS[slot * 16384];
        bf16x8 af[2][4], bfr[2][4];
#pragma unroll
        for (int kh = 0; kh < 2; ++kh)
#pragma unroll
            for (int f = 0; f < 4; ++f) {
                af[kh][f]  = *(const bf16x8*)(Ab + aoff[kh][f]);
                bfr[kh][f] = *(const bf16x8*)(Bb + boff[kh][f]);
            }
        __builtin_amdgcn_s_setprio(1);
#pragma unroll
        for (int kh = 0; kh < 2; ++kh)
#pragma unroll
            for (int mf = 0; mf < 4; ++mf)
#pragma unroll
                for (int nf = 0; nf < 4; ++nf)
                    acc[mf][nf] = __builtin_amdgcn_mfma_f32_16x16x32_bf16(
                        af[kh][mf], bfr[kh][nf], acc[mf][nf], 0, 0, 0);
        __builtin_amdgcn_s_setprio(0);

        if (kt < 14)      asm volatile("s_waitcnt vmcnt(6)" ::: "memory");
        else if (kt == 14) asm volatile("s_waitcnt vmcnt(0)" ::: "memory");
        if (kt < 15) {
            __builtin_amdgcn_s_barrier();
            asm volatile("" ::: "memory");
        }
    }

    // ---- epilogue: tanh + v_W dot over this wave's 64 o-cols
    float psum[4][4];
#pragma unroll
    for (int mf = 0; mf < 4; ++mf)
#pragma unroll
        for (int r = 0; r < 4; ++r) psum[mf][r] = 0.f;

#pragma unroll
    for (int nf = 0; nf < 4; ++nf) {
        const int o = nbq * 256 + wc * 64 + nf * 16 + t16;
        const float hbv = hb[(size_t)b * H + o];
        const float vw  = v_W[o];
#pragma unroll
        for (int mf = 0; mf < 4; ++mf)
#pragma unroll
            for (int r = 0; r < 4; ++r)
                psum[mf][r] += vw * tanh_fast(acc[mf][nf][r] + hbv);
    }
#pragma unroll
    for (int mf = 0; mf < 4; ++mf)
#pragma unroll
        for (int r = 0; r < 4; ++r) {
#pragma unroll
            for (int off = 1; off < 16; off <<= 1)
                psum[mf][r] += __shfl_xor(psum[mf][r], off, 64);
        }
    __syncthreads();   // full sync before red reuse
    if (t16 == 0) {
#pragma unroll
        for (int mf = 0; mf < 4; ++mf)
#pragma unroll
            for (int r = 0; r < 4; ++r)
                red[(wr * 64 + mf * 16 + q * 4 + r) * 4 + wc] = psum[mf][r];
    }
    __syncthreads();
    if (tid < 128) {
        float s = red[tid * 4 + 0] + red[tid * 4 + 1] + red[tid * 4 + 2] + red[tid * 4 + 3];
        pscore[(size_t)nbq * (B * S) + (size_t)Mblk * 128 + tid] = s;
    }
}

// ---------------------------------------------------------------------------
// Fallback path (r10-validated fused kernel) + its fragment-order convW.
// ---------------------------------------------------------------------------
__global__ __launch_bounds__(256) void k_convW_frag(const float* __restrict__ attn_W,
                                                    short* __restrict__ WeB2) {
    int gid = blockIdx.x * 256 + threadIdx.x;
    int lane = gid & 63;
    int kb   = (gid >> 6) & 31;
    int ot   = gid >> 11;
    int o  = ot * 16 + (lane & 15);
    int k0 = kb * 32 + (lane >> 4) * 8;
    const float* src = attn_W + (size_t)o * (2 * H) + H + k0;
    float4 a = *(const float4*)src;
    float4 c = *(const float4*)(src + 4);
    *(bf16x8*)(WeB2 + (size_t)gid * 8) = pack8(a, c);
}

__global__ __launch_bounds__(256, 2) void k_mfma_f(const float* __restrict__ enc,
                                                   const short* __restrict__ WeB2,
                                                   const float* __restrict__ v_W,
                                                   const float* __restrict__ hb,
                                                   float* __restrict__ pscore) {
    __shared__ short Abuf[2][64 * 64];

    const int tid  = threadIdx.x;
    const int lane = tid & 63;
    const int wv   = tid >> 6;
    const int t16  = lane & 15;
    const int q    = lane >> 4;

    const int L     = blockIdx.x;
    const int nbq   = (L >> 3) & 3;
    const int Mtile = (L & 7) | ((L >> 5) << 3);
    const int b  = Mtile >> 4;
    const int s0 = (Mtile & 15) * 64;

    const int am = tid >> 2;
    const int g0 = (tid & 3) * 2;
    const float* abase = enc + ((size_t)(s0 + am) * B + b) * H + g0 * 8;
    const int s7  = am & 7;
    const int ap0 = (g0 ^ s7) * 8;
    const int ap1 = ((g0 + 1) ^ s7) * 8;

    const int otb = nbq * 16 + wv * 4;
    const short* bbase = WeB2 + ((size_t)otb * 32 * 64 + lane) * 8;

    f32x4 acc[4][4];
#pragma unroll
    for (int mf = 0; mf < 4; ++mf)
#pragma unroll
        for (int nf = 0; nf < 4; ++nf) acc[mf][nf] = (f32x4){0.f, 0.f, 0.f, 0.f};

    const int swz = t16 & 7;
    const int nwv = wv * 64;

    {
        float4 v0 = *(const float4*)(abase);
        float4 v1 = *(const float4*)(abase + 4);
        float4 v2 = *(const float4*)(abase + 8);
        float4 v3 = *(const float4*)(abase + 12);
        *(bf16x8*)&Abuf[0][am * 64 + ap0] = pack8(v0, v1);
        *(bf16x8*)&Abuf[0][am * 64 + ap1] = pack8(v2, v3);
    }
    __syncthreads();

    const short* bptr = bbase;
    for (int ks = 0; ks < 16; ++ks) {
        const int cur = ks & 1;
        const int nxt = cur ^ 1;
        const bool pf = (ks < 15);
        float4 v0, v1, v2, v3;
        if (pf) {
            const float* asrc = abase + (ks + 1) * 64;
            v0 = *(const float4*)(asrc);
            v1 = *(const float4*)(asrc + 4);
            v2 = *(const float4*)(asrc + 8);
            v3 = *(const float4*)(asrc + 12);
        }

        const short* Ab = &Abuf[cur][0];
#pragma unroll
        for (int kh = 0; kh < 2; ++kh) {
            bf16x8 bfr[4];
#pragma unroll
            for (int nf = 0; nf < 4; ++nf)
                bfr[nf] = *(const bf16x8*)(bptr + nf * 16384 + kh * 512);
            const int gq = kh * 4 + q;
            const int gp = (gq ^ swz) * 8;
            bf16x8 af[4];
#pragma unroll
            for (int mf = 0; mf < 4; ++mf)
                af[mf] = *(const bf16x8*)(Ab + (mf * 16 + t16) * 64 + gp);
#pragma unroll
            for (int mf = 0; mf < 4; ++mf)
#pragma unroll
                for (int nf = 0; nf < 4; ++nf)
                    acc[mf][nf] = __builtin_amdgcn_mfma_f32_16x16x32_bf16(
                        af[mf], bfr[nf], acc[mf][nf], 0, 0, 0);
        }
        bptr += 1024;

        if (pf) {
            *(bf16x8*)&Abuf[nxt][am * 64 + ap0] = pack8(v0, v1);
            *(bf16x8*)&Abuf[nxt][am * 64 + ap1] = pack8(v2, v3);
        }
        __syncthreads();
    }

    float psum[4][4];
#pragma unroll
    for (int mf = 0; mf < 4; ++mf)
#pragma unroll
        for (int r = 0; r < 4; ++r) psum[mf][r] = 0.f;

#pragma unroll
    for (int nf = 0; nf < 4; ++nf) {
        const int o = nbq * 256 + nwv + nf * 16 + t16;
        const float hbv = hb[(size_t)b * H + o];
        const float vw  = v_W[o];
#pragma unroll
        for (int mf = 0; mf < 4; ++mf)
#pragma unroll
            for (int r = 0; r < 4; ++r)
                psum[mf][r] += vw * tanh_fast(acc[mf][nf][r] + hbv);
    }
#pragma unroll
    for (int mf = 0; mf < 4; ++mf)
#pragma unroll
        for (int r = 0; r < 4; ++r) {
#pragma unroll
            for (int off = 1; off < 16; off <<= 1)
                psum[mf][r] += __shfl_xor(psum[mf][r], off, 64);
        }

    float* red = (float*)&Abuf[0][0];
    if (t16 == 0) {
#pragma unroll
        for (int mf = 0; mf < 4; ++mf)
#pragma unroll
            for (int r = 0; r < 4; ++r)
                red[(mf * 16 + q * 4 + r) * 4 + wv] = psum[mf][r];
    }
    __syncthreads();
    if (tid < 64) {
        float s = red[tid * 4 + 0] + red[tid * 4 + 1] + red[tid * 4 + 2] + red[tid * 4 + 3];
        pscore[(size_t)nbq * (B * S) + (size_t)Mtile * 64 + tid] = s;
    }
}

// ---------------------------------------------------------------------------
// Kernel 4: combine 4 partials + mask + softmax over S. One block per b.
// ---------------------------------------------------------------------------
__global__ __launch_bounds__(256) void k_softmax(const float* __restrict__ pscore,
                                                 const int* __restrict__ mask,
                                                 float* __restrict__ out) {
    const int b = blockIdx.x;
    const int tid = threadIdx.x;
    __shared__ float sm[64];
    float v[4];
    float mx = -INFINITY;
#pragma unroll
    for (int k = 0; k < 4; ++k) {
        const int s = tid + k * 256;
        const size_t idx = (size_t)b * S + s;
        float sc = pscore[idx] + pscore[(size_t)(B * S) + idx]
                 + pscore[2 * (size_t)(B * S) + idx] + pscore[3 * (size_t)(B * S) + idx];
        sc = (mask[idx] == 0) ? -1e10f : sc;
        v[k] = sc;
        mx = fmaxf(mx, sc);
    }
#pragma unroll
    for (int off = 32; off > 0; off >>= 1) mx = fmaxf(mx, __shfl_down(mx, off, 64));
    if ((tid & 63) == 0) sm[tid >> 6] = mx;
    __syncthreads();
    if (tid == 0) {
        float m = sm[0];
        for (int k = 1; k < 4; ++k) m = fmaxf(m, sm[k]);
        sm[4] = m;
    }
    __syncthreads();
    mx = sm[4];
    float sum = 0.f;
#pragma unroll
    for (int k = 0; k < 4; ++k) { v[k] = __expf(v[k] - mx); sum += v[k]; }
#pragma unroll
    for (int off = 32; off > 0; off >>= 1) sum += __shfl_down(sum, off, 64);
    if ((tid & 63) == 0) sm[8 + (tid >> 6)] = sum;
    __syncthreads();
    if (tid == 0) sm[12] = sm[8] + sm[9] + sm[10] + sm[11];
    __syncthreads();
    const float inv = 1.f / sm[12];
#pragma unroll
    for (int k = 0; k < 4; ++k) out[(size_t)b * S + tid + k * 256] = v[k] * inv;
}

// ---------------------------------------------------------------------------
extern "C" void kernel_launch(void* const* d_in, const int* in_sizes, int n_in,
                              void* d_out, int out_size, void* d_ws, size_t ws_size,
                              hipStream_t stream) {
    const float* hidden = (const float*)d_in[0];   // (B,H)
    const float* enc    = (const float*)d_in[1];   // (S,B,H)
    const int*   mask   = (const int*)d_in[2];     // (B,S)
    const float* attn_W = (const float*)d_in[3];   // (H,2H)
    const float* attn_b = (const float*)d_in[4];   // (H,)
    const float* v_W    = (const float*)d_in[5];   // (H,)
    float* out = (float*)d_out;                    // (B,S)

    float* hb     = (float*)d_ws;                          // 64K f32   (256 KB)
    short* WeB    = (short*)(hb + (size_t)B * H);          // 1M bf16   (2 MB)
    float* pscore = (float*)(WeB + (size_t)H * H);         // 256K f32  (1 MB)
    short* encA   = (short*)(pscore + (size_t)4 * B * S);  // 64M bf16  (128 MB)

    const size_t need = (size_t)B * H * 4 + (size_t)H * H * 2
                      + (size_t)4 * B * S * 4 + (size_t)B * S * H * 2;

    k_hproj<<<dim3((B * H) / 4), 256, 0, stream>>>(hidden, attn_W, attn_b, hb);
    if (ws_size >= need) {
        k_convW<<<dim3(64), 256, 0, stream>>>(attn_W, WeB);
        k_convA<<<dim3(8192), 256, 0, stream>>>(enc, encA);
        k_mfma_s<<<dim3(2048), 512, 0, stream>>>(encA, WeB, v_W, hb, pscore);
    } else {
        k_convW_frag<<<dim3(512), 256, 0, stream>>>(attn_W, WeB);
        k_mfma_f<<<dim3(4096), 256, 0, stream>>>(enc, WeB, v_W, hb, pscore);
    }
    k_softmax<<<dim3(B), 256, 0, stream>>>(pscore, mask, out);
}

// Round 20
// 240.287 us; speedup vs baseline: 1.2576x; 1.2576x over previous
//
#include <hip/hip_runtime.h>
#include <hip/hip_bf16.h>
#include <math.h>

constexpr int B = 64, S = 1024, H = 1024;

typedef __attribute__((ext_vector_type(8))) short bf16x8;
typedef __attribute__((ext_vector_type(4))) float f32x4;

__device__ __forceinline__ unsigned pkbf2(float x, float y) {
    union { __hip_bfloat162 h; unsigned u; } r;
    r.h = __float22bfloat162_rn(float2{x, y});   // v_cvt_pk_bf16_f32 (RNE)
    return r.u;
}
__device__ __forceinline__ bf16x8 pack8(float4 a, float4 b) {
    union { unsigned u[4]; bf16x8 v; } r;
    r.u[0] = pkbf2(a.x, a.y);
    r.u[1] = pkbf2(a.z, a.w);
    r.u[2] = pkbf2(b.x, b.y);
    r.u[3] = pkbf2(b.z, b.w);
    return r.v;
}

__device__ __forceinline__ float tanh_fast(float x) {
    return 1.0f - 2.0f / (__expf(2.0f * x) + 1.0f);
}

__device__ __forceinline__ void gload_lds16(const void* g, void* l) {
    __builtin_amdgcn_global_load_lds(
        (const __attribute__((address_space(1))) unsigned int*)g,
        (__attribute__((address_space(3))) unsigned int*)(uintptr_t)l,
        16, 0, 0);
}

// ---------------------------------------------------------------------------
// Kernel 1: hb[b][o] = attn_b[o] + sum_h hidden[b,h] * attn_W[o,h]   (f32)
// ---------------------------------------------------------------------------
__global__ __launch_bounds__(256) void k_hproj(const float* __restrict__ hidden,
                                               const float* __restrict__ attn_W,
                                               const float* __restrict__ attn_b,
                                               float* __restrict__ hb) {
    int wid  = blockIdx.x * 4 + (threadIdx.x >> 6);
    int lane = threadIdx.x & 63;
    int b = wid >> 10;
    int o = wid & 1023;
    const float* hrow = hidden + (size_t)b * H;
    const float* wrow = attn_W + (size_t)o * (2 * H);
    float acc = 0.f;
#pragma unroll
    for (int k = 0; k < 4; ++k) {
        int idx = lane * 4 + k * 256;
        float4 hv = *(const float4*)(hrow + idx);
        float4 wv = *(const float4*)(wrow + idx);
        acc += hv.x * wv.x + hv.y * wv.y + hv.z * wv.z + hv.w * wv.w;
    }
#pragma unroll
    for (int off = 32; off > 0; off >>= 1) acc += __shfl_down(acc, off, 64);
    if (lane == 0) hb[(size_t)b * H + o] = acc + attn_b[o];
}

// ---------------------------------------------------------------------------
// Kernel 2: We = attn_W[:, H:] -> bf16, packed in MFMA B-fragment order
// (r15-validated). Fragment (ot, kb): lane = t16+16q holds o=ot*16+t16,
// k = kb*32+q*8..+7.  Element offset = ((ot*32 + kb)*64 + lane)*8.
// ---------------------------------------------------------------------------
__global__ __launch_bounds__(256) void k_convW(const float* __restrict__ attn_W,
                                               short* __restrict__ WeB2) {
    int gid = blockIdx.x * 256 + threadIdx.x;   // 131072 granules
    int lane = gid & 63;
    int kb   = (gid >> 6) & 31;
    int ot   = gid >> 11;
    int o  = ot * 16 + (lane & 15);
    int k0 = kb * 32 + (lane >> 4) * 8;
    const float* src = attn_W + (size_t)o * (2 * H) + H + k0;
    float4 a = *(const float4*)src;
    float4 c = *(const float4*)(src + 4);
    *(bf16x8*)(WeB2 + (size_t)gid * 8) = pack8(a, c);
}

// ---------------------------------------------------------------------------
// Kernel 3 (hybrid): fused-A stream-B MFMA GEMM.
// Grid 2048 (nbq=(L>>3)&3, Mblk=(L&7)|((L>>5)<<3): XCD partner mapping,
// verified r8). 512 thr = 8 waves (2M x 4N), wave tile 64x64, BK=64.
// A: enc f32 staged to LDS dbuf (2 x 32 KB) via global_load_lds with
//    INVERSE-SWIZZLED per-lane source (m173: linear LDS dst, src carries the
//    XOR). Converted f32->bf16 at frag-read (cvt_pk). enc read ONCE -- no
//    convA pass, no encA round-trip (the r10-vs-r15 dur_us lesson).
// B: frag-order WeB2 straight from L2, at-use (r15-validated, 165us path).
// LDS 66 KB, reg cap 128 (lb 512,4) -> 2 blocks/CU = 16 waves: per-ks
// barrier drains overlap across blocks (m97 mechanism; r19's 1-block trap
// avoided).
// ---------------------------------------------------------------------------
__global__ __launch_bounds__(512, 4) void k_mfma_h(const float* __restrict__ enc,
                                                   const short* __restrict__ WeB2,
                                                   const float* __restrict__ v_W,
                                                   const float* __restrict__ hb,
                                                   float* __restrict__ pscore) {
    __shared__ float AS[2][128 * 64];   // 64 KB: A tile f32, pair-swizzled
    __shared__ float red[128 * 4];      // 2 KB

    const int tid  = threadIdx.x;
    const int lane = tid & 63;
    const int wv   = tid >> 6;        // 0..7
    const int wr   = wv >> 2;         // 0..1  (M half)
    const int wc   = wv & 3;          // 0..3  (N quarter)
    const int t16  = lane & 15;
    const int q    = lane >> 4;

    const int L    = blockIdx.x;                  // 0..2047
    const int nbq  = (L >> 3) & 3;
    const int Mblk = (L & 7) | ((L >> 5) << 3);   // 0..511 (128 rows each)
    const int b    = Mblk >> 3;

    // ---- A staging source pointers (4 slots/thread), inverse-swizzled.
    // LDS slot s = p*512 + tid (0..2047) -> row r = s>>4, phys pair pp =
    // (s>>1)&7, half hh = s&1. Source k-pair plog = pp ^ (r&7).
    const float* arow[4];
    int koff[4];
#pragma unroll
    for (int p = 0; p < 4; ++p) {
        int slot = p * 512 + tid;
        int r  = slot >> 4;
        int pp = (slot >> 1) & 7;
        int hh = slot & 1;
        int plog = pp ^ (r & 7);
        int m = Mblk * 128 + r;
        int bb = m >> 10, ss = m & 1023;
        arow[p] = enc + ((size_t)ss * 64 + bb) * 1024;
        koff[p] = plog * 8 + hh * 4;
    }

    // ---- frag-read byte offsets within an A buffer (f32, pair-swizzled)
    int aoff[2][4];
#pragma unroll
    for (int kh = 0; kh < 2; ++kh)
#pragma unroll
        for (int mf = 0; mf < 4; ++mf) {
            int ra = wr * 64 + mf * 16 + t16;
            int phys = (kh * 4 + q) ^ (ra & 7);
            aoff[kh][mf] = ra * 64 + phys * 8;    // float index
        }

    const short* bptr = WeB2 + (size_t)(nbq * 16 + wc * 4) * 16384 + lane * 8;

    f32x4 acc[4][4];
#pragma unroll
    for (int mf = 0; mf < 4; ++mf)
#pragma unroll
        for (int nf = 0; nf < 4; ++nf) acc[mf][nf] = (f32x4){0.f, 0.f, 0.f, 0.f};

    // ---- prologue: stage ks=0 into buf 0
#pragma unroll
    for (int p = 0; p < 4; ++p)
        gload_lds16(arow[p] + koff[p],
                    (char*)&AS[0][0] + ((size_t)p * 512 + tid) * 16);
    __syncthreads();

    // ---- main loop: 16 K-tiles of 64
    for (int ks = 0; ks < 16; ++ks) {
        const int cur = ks & 1;
        const int nxt = cur ^ 1;
        if (ks + 1 < 16) {
            const int kbase = (ks + 1) * 64;
            if (nxt) {
#pragma unroll
                for (int p = 0; p < 4; ++p)
                    gload_lds16(arow[p] + kbase + koff[p],
                                (char*)&AS[1][0] + ((size_t)p * 512 + tid) * 16);
            } else {
#pragma unroll
                for (int p = 0; p < 4; ++p)
                    gload_lds16(arow[p] + kbase + koff[p],
                                (char*)&AS[0][0] + ((size_t)p * 512 + tid) * 16);
            }
        }

        const float* Ab = &AS[cur][0];
#pragma unroll
        for (int kh = 0; kh < 2; ++kh) {
            bf16x8 bfr[4];
#pragma unroll
            for (int nf = 0; nf < 4; ++nf)               // B at use, from L2
                bfr[nf] = *(const bf16x8*)(bptr + nf * 16384 + (ks * 2 + kh) * 512);
            bf16x8 af[4];
#pragma unroll
            for (int mf = 0; mf < 4; ++mf) {             // A from LDS f32 + cvt
                const float* fp = Ab + aoff[kh][mf];
                float4 x = *(const float4*)(fp);
                float4 y = *(const float4*)(fp + 4);
                af[mf] = pack8(x, y);
            }
            __builtin_amdgcn_s_setprio(1);
#pragma unroll
            for (int mf = 0; mf < 4; ++mf)
#pragma unroll
                for (int nf = 0; nf < 4; ++nf)
                    acc[mf][nf] = __builtin_amdgcn_mfma_f32_16x16x32_bf16(
                        af[mf], bfr[nf], acc[mf][nf], 0, 0, 0);
            __builtin_amdgcn_s_setprio(0);
        }
        __syncthreads();
    }

    // ---- epilogue: tanh + v_W dot over this wave's 64 o-cols
    float psum[4][4];
#pragma unroll
    for (int mf = 0; mf < 4; ++mf)
#pragma unroll
        for (int r = 0; r < 4; ++r) psum[mf][r] = 0.f;

#pragma unroll
    for (int nf = 0; nf < 4; ++nf) {
        const int o = nbq * 256 + wc * 64 + nf * 16 + t16;
        const float hbv = hb[(size_t)b * H + o];
        const float vw  = v_W[o];
#pragma unroll
        for (int mf = 0; mf < 4; ++mf)
#pragma unroll
            for (int r = 0; r < 4; ++r)
                psum[mf][r] += vw * tanh_fast(acc[mf][nf][r] + hbv);
    }
#pragma unroll
    for (int mf = 0; mf < 4; ++mf)
#pragma unroll
        for (int r = 0; r < 4; ++r) {
#pragma unroll
            for (int off = 1; off < 16; off <<= 1)
                psum[mf][r] += __shfl_xor(psum[mf][r], off, 64);
        }
    if (t16 == 0) {
#pragma unroll
        for (int mf = 0; mf < 4; ++mf)
#pragma unroll
            for (int r = 0; r < 4; ++r)
                red[(wr * 64 + mf * 16 + q * 4 + r) * 4 + wc] = psum[mf][r];
    }
    __syncthreads();
    if (tid < 128) {
        float s = red[tid * 4 + 0] + red[tid * 4 + 1] + red[tid * 4 + 2] + red[tid * 4 + 3];
        pscore[(size_t)nbq * (B * S) + (size_t)Mblk * 128 + tid] = s;
    }
}

// ---------------------------------------------------------------------------
// Kernel 4: combine 4 partials + mask + softmax over S. One block per b.
// ---------------------------------------------------------------------------
__global__ __launch_bounds__(256) void k_softmax(const float* __restrict__ pscore,
                                                 const int* __restrict__ mask,
                                                 float* __restrict__ out) {
    const int b = blockIdx.x;
    const int tid = threadIdx.x;
    __shared__ float sm[64];
    float v[4];
    float mx = -INFINITY;
#pragma unroll
    for (int k = 0; k < 4; ++k) {
        const int s = tid + k * 256;
        const size_t idx = (size_t)b * S + s;
        float sc = pscore[idx] + pscore[(size_t)(B * S) + idx]
                 + pscore[2 * (size_t)(B * S) + idx] + pscore[3 * (size_t)(B * S) + idx];
        sc = (mask[idx] == 0) ? -1e10f : sc;
        v[k] = sc;
        mx = fmaxf(mx, sc);
    }
#pragma unroll
    for (int off = 32; off > 0; off >>= 1) mx = fmaxf(mx, __shfl_down(mx, off, 64));
    if ((tid & 63) == 0) sm[tid >> 6] = mx;
    __syncthreads();
    if (tid == 0) {
        float m = sm[0];
        for (int k = 1; k < 4; ++k) m = fmaxf(m, sm[k]);
        sm[4] = m;
    }
    __syncthreads();
    mx = sm[4];
    float sum = 0.f;
#pragma unroll
    for (int k = 0; k < 4; ++k) { v[k] = __expf(v[k] - mx); sum += v[k]; }
#pragma unroll
    for (int off = 32; off > 0; off >>= 1) sum += __shfl_down(sum, off, 64);
    if ((tid & 63) == 0) sm[8 + (tid >> 6)] = sum;
    __syncthreads();
    if (tid == 0) sm[12] = sm[8] + sm[9] + sm[10] + sm[11];
    __syncthreads();
    const float inv = 1.f / sm[12];
#pragma unroll
    for (int k = 0; k < 4; ++k) out[(size_t)b * S + tid + k * 256] = v[k] * inv;
}

// ---------------------------------------------------------------------------
extern "C" void kernel_launch(void* const* d_in, const int* in_sizes, int n_in,
                              void* d_out, int out_size, void* d_ws, size_t ws_size,
                              hipStream_t stream) {
    const float* hidden = (const float*)d_in[0];   // (B,H)
    const float* enc    = (const float*)d_in[1];   // (S,B,H)
    const int*   mask   = (const int*)d_in[2];     // (B,S)
    const float* attn_W = (const float*)d_in[3];   // (H,2H)
    const float* attn_b = (const float*)d_in[4];   // (H,)
    const float* v_W    = (const float*)d_in[5];   // (H,)
    float* out = (float*)d_out;                    // (B,S)

    float* hb     = (float*)d_ws;                          // 64K f32   (256 KB)
    short* WeB2   = (short*)(hb + (size_t)B * H);          // 1M bf16   (2 MB)
    float* pscore = (float*)(WeB2 + (size_t)H * H);        // 256K f32  (1 MB)

    k_hproj<<<dim3((B * H) / 4), 256, 0, stream>>>(hidden, attn_W, attn_b, hb);
    k_convW<<<dim3(512), 256, 0, stream>>>(attn_W, WeB2);
    k_mfma_h<<<dim3(2048), 512, 0, stream>>>(enc, WeB2, v_W, hb, pscore);
    k_softmax<<<dim3(B), 256, 0, stream>>>(pscore, mask, out);
}

// Round 22
// 239.887 us; speedup vs baseline: 1.2596x; 1.0017x over previous
//
#include <hip/hip_runtime.h>
#include <hip/hip_bf16.h>
#include <math.h>

constexpr int B = 64, S = 1024, H = 1024;

typedef __attribute__((ext_vector_type(8))) short bf16x8;
typedef __attribute__((ext_vector_type(4))) float f32x4;

__device__ __forceinline__ unsigned pkbf2(float x, float y) {
    union { __hip_bfloat162 h; unsigned u; } r;
    r.h = __float22bfloat162_rn(float2{x, y});   // v_cvt_pk_bf16_f32 (RNE)
    return r.u;
}
__device__ __forceinline__ bf16x8 pack8(float4 a, float4 b) {
    union { unsigned u[4]; bf16x8 v; } r;
    r.u[0] = pkbf2(a.x, a.y);
    r.u[1] = pkbf2(a.z, a.w);
    r.u[2] = pkbf2(b.x, b.y);
    r.u[3] = pkbf2(b.z, b.w);
    return r.v;
}

__device__ __forceinline__ float tanh_fast(float x) {
    return 1.0f - 2.0f / (__expf(2.0f * x) + 1.0f);
}

__device__ __forceinline__ void gload_lds16(const void* g, void* l) {
    __builtin_amdgcn_global_load_lds(
        (const __attribute__((address_space(1))) unsigned int*)g,
        (__attribute__((address_space(3))) unsigned int*)(uintptr_t)l,
        16, 0, 0);
}

// ---------------------------------------------------------------------------
// Kernel 1: hb[b][o] = attn_b[o] + sum_h hidden[b,h] * attn_W[o,h]   (f32)
// ---------------------------------------------------------------------------
__global__ __launch_bounds__(256) void k_hproj(const float* __restrict__ hidden,
                                               const float* __restrict__ attn_W,
                                               const float* __restrict__ attn_b,
                                               float* __restrict__ hb) {
    int wid  = blockIdx.x * 4 + (threadIdx.x >> 6);
    int lane = threadIdx.x & 63;
    int b = wid >> 10;
    int o = wid & 1023;
    const float* hrow = hidden + (size_t)b * H;
    const float* wrow = attn_W + (size_t)o * (2 * H);
    float acc = 0.f;
#pragma unroll
    for (int k = 0; k < 4; ++k) {
        int idx = lane * 4 + k * 256;
        float4 hv = *(const float4*)(hrow + idx);
        float4 wv = *(const float4*)(wrow + idx);
        acc += hv.x * wv.x + hv.y * wv.y + hv.z * wv.z + hv.w * wv.w;
    }
#pragma unroll
    for (int off = 32; off > 0; off >>= 1) acc += __shfl_down(acc, off, 64);
    if (lane == 0) hb[(size_t)b * H + o] = acc + attn_b[o];
}

// ---------------------------------------------------------------------------
// Kernel 2: We = attn_W[:, H:] -> bf16, packed in MFMA B-fragment order
// (r15-validated). Fragment (ot, kb): lane = t16+16q holds o=ot*16+t16,
// k = kb*32+q*8..+7.  Element offset = ((ot*32 + kb)*64 + lane)*8.
// ---------------------------------------------------------------------------
__global__ __launch_bounds__(256) void k_convW(const float* __restrict__ attn_W,
                                               short* __restrict__ WeB2) {
    int gid = blockIdx.x * 256 + threadIdx.x;   // 131072 granules
    int lane = gid & 63;
    int kb   = (gid >> 6) & 31;
    int ot   = gid >> 11;
    int o  = ot * 16 + (lane & 15);
    int k0 = kb * 32 + (lane >> 4) * 8;
    const float* src = attn_W + (size_t)o * (2 * H) + H + k0;
    float4 a = *(const float4*)src;
    float4 c = *(const float4*)(src + 4);
    *(bf16x8*)(WeB2 + (size_t)gid * 8) = pack8(a, c);
}

// ---------------------------------------------------------------------------
// Kernel 3 (hybrid): fused-A stream-B MFMA GEMM (r20 structure, 240us total).
// r21 fix: A swizzle moved from 32B-pair to FLOAT4 (16B) granularity --
// r20's pair swizzle put x-reads on even bank-groups only (2x conflict,
// SQ_LDS_BANK_CONFLICT 1.68e7). Now physical j4 = logical j4 ^ (r&7):
// per-instruction bank groups (2q)^(t16&7) cover all 8 uniformly (the
// exact pattern the bf16 kernels measured at 0 conflicts).
// ---------------------------------------------------------------------------
__global__ __launch_bounds__(512, 4) void k_mfma_h(const float* __restrict__ enc,
                                                   const short* __restrict__ WeB2,
                                                   const float* __restrict__ v_W,
                                                   const float* __restrict__ hb,
                                                   float* __restrict__ pscore) {
    __shared__ float AS[2][128 * 64];   // 64 KB: A tile f32, float4-swizzled
    __shared__ float red[128 * 4];      // 2 KB

    const int tid  = threadIdx.x;
    const int lane = tid & 63;
    const int wv   = tid >> 6;        // 0..7
    const int wr   = wv >> 2;         // 0..1  (M half)
    const int wc   = wv & 3;          // 0..3  (N quarter)
    const int t16  = lane & 15;
    const int q    = lane >> 4;

    const int L    = blockIdx.x;                  // 0..2047
    const int nbq  = (L >> 3) & 3;
    const int Mblk = (L & 7) | ((L >> 5) << 3);   // 0..511 (128 rows each)
    const int b    = Mblk >> 3;

    // ---- A staging source (4 slots/thread), inverse-swizzled at float4 level.
    // Slot s -> row r = s>>4, physical float4 slot j4p = s&15;
    // logical j4 = j4p ^ (r&7)  (low-3-bit involution, bit3 preserved).
    const float* arow[4];
    int koff[4];
#pragma unroll
    for (int p = 0; p < 4; ++p) {
        int slot = p * 512 + tid;
        int r   = slot >> 4;
        int j4p = slot & 15;
        int j4  = j4p ^ (r & 7);
        int m = Mblk * 128 + r;
        int bb = m >> 10, ss = m & 1023;
        arow[p] = enc + ((size_t)ss * 64 + bb) * 1024;
        koff[p] = j4 * 4;
    }

    // ---- frag-read float offsets (x and y float4 independently swizzled)
    int aoffx[2][4], aoffy[2][4];
#pragma unroll
    for (int kh = 0; kh < 2; ++kh)
#pragma unroll
        for (int mf = 0; mf < 4; ++mf) {
            int ra  = wr * 64 + mf * 16 + t16;
            int kq2 = (kh * 4 + q) * 2;
            aoffx[kh][mf] = ra * 64 + ((kq2)     ^ (ra & 7)) * 4;
            aoffy[kh][mf] = ra * 64 + ((kq2 + 1) ^ (ra & 7)) * 4;
        }

    const short* bptr = WeB2 + (size_t)(nbq * 16 + wc * 4) * 16384 + lane * 8;

    f32x4 acc[4][4];
#pragma unroll
    for (int mf = 0; mf < 4; ++mf)
#pragma unroll
        for (int nf = 0; nf < 4; ++nf) acc[mf][nf] = (f32x4){0.f, 0.f, 0.f, 0.f};

    // ---- prologue: stage ks=0 into buf 0
#pragma unroll
    for (int p = 0; p < 4; ++p)
        gload_lds16(arow[p] + koff[p],
                    (char*)&AS[0][0] + ((size_t)p * 512 + tid) * 16);
    __syncthreads();

    // ---- main loop: 16 K-tiles of 64
    for (int ks = 0; ks < 16; ++ks) {
        const int cur = ks & 1;
        const int nxt = cur ^ 1;
        if (ks + 1 < 16) {
            const int kbase = (ks + 1) * 64;
            if (nxt) {
#pragma unroll
                for (int p = 0; p < 4; ++p)
                    gload_lds16(arow[p] + kbase + koff[p],
                                (char*)&AS[1][0] + ((size_t)p * 512 + tid) * 16);
            } else {
#pragma unroll
                for (int p = 0; p < 4; ++p)
                    gload_lds16(arow[p] + kbase + koff[p],
                                (char*)&AS[0][0] + ((size_t)p * 512 + tid) * 16);
            }
        }

        const float* Ab = &AS[cur][0];
#pragma unroll
        for (int kh = 0; kh < 2; ++kh) {
            bf16x8 bfr[4];
#pragma unroll
            for (int nf = 0; nf < 4; ++nf)               // B at use, from L2
                bfr[nf] = *(const bf16x8*)(bptr + nf * 16384 + (ks * 2 + kh) * 512);
            bf16x8 af[4];
#pragma unroll
            for (int mf = 0; mf < 4; ++mf) {             // A from LDS f32 + cvt
                float4 x = *(const float4*)(Ab + aoffx[kh][mf]);
                float4 y = *(const float4*)(Ab + aoffy[kh][mf]);
                af[mf] = pack8(x, y);
            }
            __builtin_amdgcn_s_setprio(1);
#pragma unroll
            for (int mf = 0; mf < 4; ++mf)
#pragma unroll
                for (int nf = 0; nf < 4; ++nf)
                    acc[mf][nf] = __builtin_amdgcn_mfma_f32_16x16x32_bf16(
                        af[mf], bfr[nf], acc[mf][nf], 0, 0, 0);
            __builtin_amdgcn_s_setprio(0);
        }
        __syncthreads();
    }

    // ---- epilogue: tanh + v_W dot over this wave's 64 o-cols
    float psum[4][4];
#pragma unroll
    for (int mf = 0; mf < 4; ++mf)
#pragma unroll
        for (int r = 0; r < 4; ++r) psum[mf][r] = 0.f;

#pragma unroll
    for (int nf = 0; nf < 4; ++nf) {
        const int o = nbq * 256 + wc * 64 + nf * 16 + t16;
        const float hbv = hb[(size_t)b * H + o];
        const float vw  = v_W[o];
#pragma unroll
        for (int mf = 0; mf < 4; ++mf)
#pragma unroll
            for (int r = 0; r < 4; ++r)
                psum[mf][r] += vw * tanh_fast(acc[mf][nf][r] + hbv);
    }
#pragma unroll
    for (int mf = 0; mf < 4; ++mf)
#pragma unroll
        for (int r = 0; r < 4; ++r) {
#pragma unroll
            for (int off = 1; off < 16; off <<= 1)
                psum[mf][r] += __shfl_xor(psum[mf][r], off, 64);
        }
    if (t16 == 0) {
#pragma unroll
        for (int mf = 0; mf < 4; ++mf)
#pragma unroll
            for (int r = 0; r < 4; ++r)
                red[(wr * 64 + mf * 16 + q * 4 + r) * 4 + wc] = psum[mf][r];
    }
    __syncthreads();
    if (tid < 128) {
        float s = red[tid * 4 + 0] + red[tid * 4 + 1] + red[tid * 4 + 2] + red[tid * 4 + 3];
        pscore[(size_t)nbq * (B * S) + (size_t)Mblk * 128 + tid] = s;
    }
}

// ---------------------------------------------------------------------------
// Kernel 4: combine 4 partials + mask + softmax over S. One block per b.
// ---------------------------------------------------------------------------
__global__ __launch_bounds__(256) void k_softmax(const float* __restrict__ pscore,
                                                 const int* __restrict__ mask,
                                                 float* __restrict__ out) {
    const int b = blockIdx.x;
    const int tid = threadIdx.x;
    __shared__ float sm[64];
    float v[4];
    float mx = -INFINITY;
#pragma unroll
    for (int k = 0; k < 4; ++k) {
        const int s = tid + k * 256;
        const size_t idx = (size_t)b * S + s;
        float sc = pscore[idx] + pscore[(size_t)(B * S) + idx]
                 + pscore[2 * (size_t)(B * S) + idx] + pscore[3 * (size_t)(B * S) + idx];
        sc = (mask[idx] == 0) ? -1e10f : sc;
        v[k] = sc;
        mx = fmaxf(mx, sc);
    }
#pragma unroll
    for (int off = 32; off > 0; off >>= 1) mx = fmaxf(mx, __shfl_down(mx, off, 64));
    if ((tid & 63) == 0) sm[tid >> 6] = mx;
    __syncthreads();
    if (tid == 0) {
        float m = sm[0];
        for (int k = 1; k < 4; ++k) m = fmaxf(m, sm[k]);
        sm[4] = m;
    }
    __syncthreads();
    mx = sm[4];
    float sum = 0.f;
#pragma unroll
    for (int k = 0; k < 4; ++k) { v[k] = __expf(v[k] - mx); sum += v[k]; }
#pragma unroll
    for (int off = 32; off > 0; off >>= 1) sum += __shfl_down(sum, off, 64);
    if ((tid & 63) == 0) sm[8 + (tid >> 6)] = sum;
    __syncthreads();
    if (tid == 0) sm[12] = sm[8] + sm[9] + sm[10] + sm[11];
    __syncthreads();
    const float inv = 1.f / sm[12];
#pragma unroll
    for (int k = 0; k < 4; ++k) out[(size_t)b * S + tid + k * 256] = v[k] * inv;
}

// ---------------------------------------------------------------------------
extern "C" void kernel_launch(void* const* d_in, const int* in_sizes, int n_in,
                              void* d_out, int out_size, void* d_ws, size_t ws_size,
                              hipStream_t stream) {
    const float* hidden = (const float*)d_in[0];   // (B,H)
    const float* enc    = (const float*)d_in[1];   // (S,B,H)
    const int*   mask   = (const int*)d_in[2];     // (B,S)
    const float* attn_W = (const float*)d_in[3];   // (H,2H)
    const float* attn_b = (const float*)d_in[4];   // (H,)
    const float* v_W    = (const float*)d_in[5];   // (H,)
    float* out = (float*)d_out;                    // (B,S)

    float* hb     = (float*)d_ws;                          // 64K f32   (256 KB)
    short* WeB2   = (short*)(hb + (size_t)B * H);          // 1M bf16   (2 MB)
    float* pscore = (float*)(WeB2 + (size_t)H * H);        // 256K f32  (1 MB)

    k_hproj<<<dim3((B * H) / 4), 256, 0, stream>>>(hidden, attn_W, attn_b, hb);
    k_convW<<<dim3(512), 256, 0, stream>>>(attn_W, WeB2);
    k_mfma_h<<<dim3(2048), 512, 0, stream>>>(enc, WeB2, v_W, hb, pscore);
    k_softmax<<<dim3(B), 256, 0, stream>>>(pscore, mask, out);
}

// Round 25
// 210.765 us; speedup vs baseline: 1.4337x; 1.1382x over previous
//
#include <hip/hip_runtime.h>
#include <hip/hip_bf16.h>
#include <math.h>

constexpr int B = 64, S = 1024, H = 1024;

typedef __attribute__((ext_vector_type(8))) short bf16x8;
typedef __attribute__((ext_vector_type(4))) float f32x4;

__device__ __forceinline__ unsigned pkbf2(float x, float y) {
    union { __hip_bfloat162 h; unsigned u; } r;
    r.h = __float22bfloat162_rn(float2{x, y});   // v_cvt_pk_bf16_f32 (RNE)
    return r.u;
}
__device__ __forceinline__ bf16x8 pack8(float4 a, float4 b) {
    union { unsigned u[4]; bf16x8 v; } r;
    r.u[0] = pkbf2(a.x, a.y);
    r.u[1] = pkbf2(a.z, a.w);
    r.u[2] = pkbf2(b.x, b.y);
    r.u[3] = pkbf2(b.z, b.w);
    return r.v;
}

__device__ __forceinline__ float tanh_fast(float x) {
    return 1.0f - 2.0f / (__expf(2.0f * x) + 1.0f);
}

// ---------------------------------------------------------------------------
// Kernel 1: hb[b][o] = attn_b[o] + sum_h hidden[b,h] * attn_W[o,h]   (f32)
// ---------------------------------------------------------------------------
__global__ __launch_bounds__(256) void k_hproj(const float* __restrict__ hidden,
                                               const float* __restrict__ attn_W,
                                               const float* __restrict__ attn_b,
                                               float* __restrict__ hb) {
    int wid  = blockIdx.x * 4 + (threadIdx.x >> 6);
    int lane = threadIdx.x & 63;
    int b = wid >> 10;
    int o = wid & 1023;
    const float* hrow = hidden + (size_t)b * H;
    const float* wrow = attn_W + (size_t)o * (2 * H);
    float acc = 0.f;
#pragma unroll
    for (int k = 0; k < 4; ++k) {
        int idx = lane * 4 + k * 256;
        float4 hv = *(const float4*)(hrow + idx);
        float4 wv = *(const float4*)(wrow + idx);
        acc += hv.x * wv.x + hv.y * wv.y + hv.z * wv.z + hv.w * wv.w;
    }
#pragma unroll
    for (int off = 32; off > 0; off >>= 1) acc += __shfl_down(acc, off, 64);
    if (lane == 0) hb[(size_t)b * H + o] = acc + attn_b[o];
}

// ---------------------------------------------------------------------------
// Kernel 2: We = attn_W[:, H:] -> bf16, MFMA B-fragment order (r15-validated).
// ---------------------------------------------------------------------------
__global__ __launch_bounds__(256) void k_convW(const float* __restrict__ attn_W,
                                               short* __restrict__ WeB2) {
    int gid = blockIdx.x * 256 + threadIdx.x;   // 131072 granules
    int lane = gid & 63;
    int kb   = (gid >> 6) & 31;
    int ot   = gid >> 11;
    int o  = ot * 16 + (lane & 15);
    int k0 = kb * 32 + (lane >> 4) * 8;
    const float* src = attn_W + (size_t)o * (2 * H) + H + k0;
    float4 a = *(const float4*)src;
    float4 c = *(const float4*)(src + 4);
    *(bf16x8*)(WeB2 + (size_t)gid * 8) = pack8(a, c);
}

// ---------------------------------------------------------------------------
// Kernel 3 (r23): reg-staged cross-barrier prefetch MFMA GEMM.
// r10 skeleton (64x256 block, 4 waves, bf16 A-LDS dbuf, B at-use from L2)
// with the prefetch RESTRUCTURED so the barrier's implicit vmcnt(0) drain
// (the m97 stall) never waits on in-flight loads:
//   top of ks:  cvt+ds_write data(ks+1) from regs loaded during ks-1
//               issue plain loads for data(ks+2) -> regs (carried over barrier)
//   body:       B at-use + A frags from Abuf[ks&1] + MFMA
//   barrier:    vmcnt already drained by the cvt consumption -> no stall.
// Slot safety: top-of-ks writes Abuf[(ks+1)&1]; its readers were at ks-1 and
// passed the end-of-(ks-1) barrier. End-of-ks barrier separates this ks's
// readers of Abuf[ks&1] from top-of-(ks+1) writes into the same buffer.
// lb(256,3): ~104 VGPR + 64 acc = 168 <= 170 -> 3 blocks/CU (12 waves,
// 3 independent barrier groups). No setprio (m190: hurts lockstep).
// ---------------------------------------------------------------------------
__global__ __launch_bounds__(256, 3) void k_mfma_r(const float* __restrict__ enc,
                                                   const short* __restrict__ WeB2,
                                                   const float* __restrict__ v_W,
                                                   const float* __restrict__ hb,
                                                   float* __restrict__ pscore) {
    __shared__ short Abuf[2][64 * 64];    // 16 KB total
    __shared__ float red[64 * 4];         // 1 KB

    const int tid  = threadIdx.x;
    const int lane = tid & 63;
    const int wv   = tid >> 6;        // 0..3 (N quarter)
    const int t16  = lane & 15;
    const int q    = lane >> 4;

    const int L     = blockIdx.x;                  // 0..4095
    const int nbq   = (L >> 3) & 3;
    const int Mtile = (L & 7) | ((L >> 5) << 3);   // 0..1023 (64 rows each)
    const int b  = Mtile >> 4;
    const int s0 = (Mtile & 15) * 64;

    // A staging roles: 4 threads per row, 16 consecutive floats (2 granules)
    const int am = tid >> 2;          // row 0..63
    const int g0 = (tid & 3) * 2;     // granule 0,2,4,6
    const float* abase = enc + ((size_t)(s0 + am) * B + b) * H + g0 * 8;
    const int s7  = am & 7;
    const int ap0 = (g0 ^ s7) * 8;
    const int ap1 = ((g0 + 1) ^ s7) * 8;

    const int otb = nbq * 16 + wv * 4;
    const short* bptr = WeB2 + ((size_t)otb * 32 * 64 + lane) * 8;

    f32x4 acc[4][4];
#pragma unroll
    for (int mf = 0; mf < 4; ++mf)
#pragma unroll
        for (int nf = 0; nf < 4; ++nf) acc[mf][nf] = (f32x4){0.f, 0.f, 0.f, 0.f};

    const int swz = t16 & 7;
    const int nwv = wv * 64;

    float4 v0, v1, v2, v3;            // carried prefetch regs (16 VGPR)

    // ---- prologue: data(0) -> slot0 directly; issue loads for data(1)
    {
        float4 a0 = *(const float4*)(abase);
        float4 a1 = *(const float4*)(abase + 4);
        float4 a2 = *(const float4*)(abase + 8);
        float4 a3 = *(const float4*)(abase + 12);
        *(bf16x8*)&Abuf[0][am * 64 + ap0] = pack8(a0, a1);
        *(bf16x8*)&Abuf[0][am * 64 + ap1] = pack8(a2, a3);
        const float* asrc = abase + 64;
        v0 = *(const float4*)(asrc);
        v1 = *(const float4*)(asrc + 4);
        v2 = *(const float4*)(asrc + 8);
        v3 = *(const float4*)(asrc + 12);
    }
    __syncthreads();

    // ---- main loop: 16 K-tiles of 64
    for (int ks = 0; ks < 16; ++ks) {
        const int cur = ks & 1;
        const int nxt = cur ^ 1;

        // write data(ks+1) from carried regs (loads issued last iteration)
        if (ks + 1 < 16) {
            *(bf16x8*)&Abuf[nxt][am * 64 + ap0] = pack8(v0, v1);
            *(bf16x8*)&Abuf[nxt][am * 64 + ap1] = pack8(v2, v3);
        }
        // issue loads for data(ks+2) -> carried regs
        if (ks + 2 < 16) {
            const float* asrc = abase + (ks + 2) * 64;
            v0 = *(const float4*)(asrc);
            v1 = *(const float4*)(asrc + 4);
            v2 = *(const float4*)(asrc + 8);
            v3 = *(const float4*)(asrc + 12);
        }

        const short* Ab = &Abuf[cur][0];
#pragma unroll
        for (int kh = 0; kh < 2; ++kh) {
            bf16x8 bfr[4];
#pragma unroll
            for (int nf = 0; nf < 4; ++nf)               // B at use, from L2
                bfr[nf] = *(const bf16x8*)(bptr + nf * 16384 + (ks * 2 + kh) * 512);
            const int gq = kh * 4 + q;
            const int gp = (gq ^ swz) * 8;
            bf16x8 af[4];
#pragma unroll
            for (int mf = 0; mf < 4; ++mf)
                af[mf] = *(const bf16x8*)(Ab + (mf * 16 + t16) * 64 + gp);
#pragma unroll
            for (int mf = 0; mf < 4; ++mf)
#pragma unroll
                for (int nf = 0; nf < 4; ++nf)
                    acc[mf][nf] = __builtin_amdgcn_mfma_f32_16x16x32_bf16(
                        af[mf], bfr[nf], acc[mf][nf], 0, 0, 0);
        }
        __syncthreads();
    }

    // ---- epilogue: tanh + v_W dot over this wave's 64 o-cols
    float psum[4][4];
#pragma unroll
    for (int mf = 0; mf < 4; ++mf)
#pragma unroll
        for (int r = 0; r < 4; ++r) psum[mf][r] = 0.f;

#pragma unroll
    for (int nf = 0; nf < 4; ++nf) {
        const int o = nbq * 256 + nwv + nf * 16 + t16;
        const float hbv = hb[(size_t)b * H + o];
        const float vw  = v_W[o];
#pragma unroll
        for (int mf = 0; mf < 4; ++mf)
#pragma unroll
            for (int r = 0; r < 4; ++r)
                psum[mf][r] += vw * tanh_fast(acc[mf][nf][r] + hbv);
    }
#pragma unroll
    for (int mf = 0; mf < 4; ++mf)
#pragma unroll
        for (int r = 0; r < 4; ++r) {
#pragma unroll
            for (int off = 1; off < 16; off <<= 1)
                psum[mf][r] += __shfl_xor(psum[mf][r], off, 64);
        }
    if (t16 == 0) {
#pragma unroll
        for (int mf = 0; mf < 4; ++mf)
#pragma unroll
            for (int r = 0; r < 4; ++r)
                red[(mf * 16 + q * 4 + r) * 4 + wv] = psum[mf][r];
    }
    __syncthreads();
    if (tid < 64) {
        float s = red[tid * 4 + 0] + red[tid * 4 + 1] + red[tid * 4 + 2] + red[tid * 4 + 3];
        pscore[(size_t)nbq * (B * S) + (size_t)Mtile * 64 + tid] = s;
    }
}

// ---------------------------------------------------------------------------
// Kernel 4: combine 4 partials + mask + softmax over S. One block per b.
// ---------------------------------------------------------------------------
__global__ __launch_bounds__(256) void k_softmax(const float* __restrict__ pscore,
                                                 const int* __restrict__ mask,
                                                 float* __restrict__ out) {
    const int b = blockIdx.x;
    const int tid = threadIdx.x;
    __shared__ float sm[64];
    float v[4];
    float mx = -INFINITY;
#pragma unroll
    for (int k = 0; k < 4; ++k) {
        const int s = tid + k * 256;
        const size_t idx = (size_t)b * S + s;
        float sc = pscore[idx] + pscore[(size_t)(B * S) + idx]
                 + pscore[2 * (size_t)(B * S) + idx] + pscore[3 * (size_t)(B * S) + idx];
        sc = (mask[idx] == 0) ? -1e10f : sc;
        v[k] = sc;
        mx = fmaxf(mx, sc);
    }
#pragma unroll
    for (int off = 32; off > 0; off >>= 1) mx = fmaxf(mx, __shfl_down(mx, off, 64));
    if ((tid & 63) == 0) sm[tid >> 6] = mx;
    __syncthreads();
    if (tid == 0) {
        float m = sm[0];
        for (int k = 1; k < 4; ++k) m = fmaxf(m, sm[k]);
        sm[4] = m;
    }
    __syncthreads();
    mx = sm[4];
    float sum = 0.f;
#pragma unroll
    for (int k = 0; k < 4; ++k) { v[k] = __expf(v[k] - mx); sum += v[k]; }
#pragma unroll
    for (int off = 32; off > 0; off >>= 1) sum += __shfl_down(sum, off, 64);
    if ((tid & 63) == 0) sm[8 + (tid >> 6)] = sum;
    __syncthreads();
    if (tid == 0) sm[12] = sm[8] + sm[9] + sm[10] + sm[11];
    __syncthreads();
    const float inv = 1.f / sm[12];
#pragma unroll
    for (int k = 0; k < 4; ++k) out[(size_t)b * S + tid + k * 256] = v[k] * inv;
}

// ---------------------------------------------------------------------------
extern "C" void kernel_launch(void* const* d_in, const int* in_sizes, int n_in,
                              void* d_out, int out_size, void* d_ws, size_t ws_size,
                              hipStream_t stream) {
    const float* hidden = (const float*)d_in[0];   // (B,H)
    const float* enc    = (const float*)d_in[1];   // (S,B,H)
    const int*   mask   = (const int*)d_in[2];     // (B,S)
    const float* attn_W = (const float*)d_in[3];   // (H,2H)
    const float* attn_b = (const float*)d_in[4];   // (H,)
    const float* v_W    = (const float*)d_in[5];   // (H,)
    float* out = (float*)d_out;                    // (B,S)

    float* hb     = (float*)d_ws;                          // 64K f32   (256 KB)
    short* WeB2   = (short*)(hb + (size_t)B * H);          // 1M bf16   (2 MB)
    float* pscore = (float*)(WeB2 + (size_t)H * H);        // 256K f32  (1 MB)

    k_hproj<<<dim3((B * H) / 4), 256, 0, stream>>>(hidden, attn_W, attn_b, hb);
    k_convW<<<dim3(512), 256, 0, stream>>>(attn_W, WeB2);
    k_mfma_r<<<dim3(4096), 256, 0, stream>>>(enc, WeB2, v_W, hb, pscore);
    k_softmax<<<dim3(B), 256, 0, stream>>>(pscore, mask, out);
}